// Round 12
// baseline (505.306 us; speedup 1.0000x reference)
//
#include <hip/hip_runtime.h>
#include <math.h>

typedef __bf16 bf16x8 __attribute__((ext_vector_type(8)));
typedef float  f32x16 __attribute__((ext_vector_type(16)));

#define DEVFN __device__ __forceinline__

DEVFN unsigned short f2bfh(float f) {
    __bf16 h = (__bf16)f;
    union { __bf16 h; unsigned short u; } v; v.h = h;
    return v.u;
}
DEVFN float sigmoidf_(float x) { return 1.0f / (1.0f + expf(-x)); }

// fold per-channel sums (bnp[c*2]=s, [c*2+1]=s2) -> scale/offset in LDS
#define BN_FOLD1(bnp, gamma, beta, N, abs_, abo_, tid)                      \
    if (tid < 24) {                                                          \
        float s_  = (bnp)[(tid)*2];                                          \
        float s2_ = (bnp)[(tid)*2 + 1];                                      \
        float m_ = s_ / (N);                                                 \
        float v_ = s2_ / (N) - m_*m_;                                        \
        float r_ = rsqrtf(v_ + 1e-5f);                                       \
        float a_ = (gamma)[tid] * r_;                                        \
        (abs_)[tid] = a_; (abo_)[tid] = (beta)[tid] - m_*a_;                 \
    }

// wave-64 sum reduce
DEVFN float wsum(float v) {
    #pragma unroll
    for (int off = 32; off > 0; off >>= 1) v += __shfl_down(v, off);
    return v;
}

// --------- merged: conv1 (blocks 0..1023) + weight prep (1024..2111) ------
// conv1: R5/R7/R8 lesson: accumulators must be NAMED SCALARS (arrays spill).
// bn1 partials accumulated in-kernel (wave reduce + atomicAdd).
__launch_bounds__(256, 4)
__global__ void prep_conv1_kernel(const float* __restrict__ img, const float* __restrict__ wk,
                                  const float* __restrict__ cb, float* __restrict__ y1,
                                  float* __restrict__ bnp1,
                                  const float* __restrict__ Wg2, const float* __restrict__ Wg3,
                                  const float* __restrict__ Wg4,
                                  const float* __restrict__ Wih, const float* __restrict__ Whh,
                                  unsigned short* __restrict__ Wt2, unsigned short* __restrict__ Wt3,
                                  unsigned short* __restrict__ Wt4,
                                  float* __restrict__ WihT, float* __restrict__ WhhT)
{
    int blk = blockIdx.x, tid = threadIdx.x;
    if (blk >= 1024) {                                 // ---- weight prep
        int i = (blk - 1024) * 256 + tid;              // < 278528
        if (i < 196608) {                              // Wg -> bf16 [k/8][col][8]
            int seg = i >> 16, idx = i & 65535;
            const float* src = (seg == 0) ? Wg2 : (seg == 1) ? Wg3 : Wg4;
            unsigned short* dst = (seg == 0) ? Wt2 : (seg == 1) ? Wt3 : Wt4;
            int col = idx >> 8, k = idx & 255;
            dst[(k >> 3)*2048 + col*8 + (k & 7)] = f2bfh(src[idx]);
        } else {
            int j = i - 196608;
            if (j < 65536) {                           // WhhT[d][row]
                int d = j >> 9, row = j & 511;
                WhhT[j] = Whh[row*128 + d];
            } else {
                j -= 65536;                            // WihT[d][row]
                int d = j >> 9, row = j & 511;
                WihT[j] = Wih[row*32 + d];
            }
        }
        return;
    }
    // ---- conv1 (3->24), block (b, t): oh rows 4t..4t+3
    __shared__ float simg[3][9][128];
    __shared__ __align__(16) float wl[3][9][24];
    __shared__ float cbs[24];
    __shared__ float bs[4][24], bs2[4][24];
    int b = blk >> 4, t = blk & 15;
    for (int i = tid; i < 648; i += 256) {
        int co = i / 27, rem = i % 27;
        wl[rem / 9][rem % 9][co] = wk[i];
    }
    if (tid < 24) cbs[tid] = cb[tid];
    for (int i = tid; i < 96; i += 256) { bs[i / 24][i % 24] = 0.f; bs2[i / 24][i % 24] = 0.f; }
    int base = 8*t - 1;
    for (int i = tid; i < 3*9*128; i += 256) {
        int ci = i / (9*128); int r2 = i % (9*128);
        int row = r2 / 128, colx = r2 % 128;
        int ih = base + row;
        simg[ci][row][colx] = (ih >= 0 && ih < 128) ?
            img[((size_t)(b*3 + ci)*128 + ih)*128 + colx] : 0.f;
    }
    __syncthreads();

    int ow = tid & 63;
    int os = tid >> 6;
    int oh = t*4 + os;
    int wv = tid >> 6, ln = tid & 63;
    float* yb = y1 + ((size_t)b*24*64 + oh)*64 + ow;

    #pragma unroll
    for (int co4 = 0; co4 < 24; co4 += 4) {
        float a0 = 0.f, a1 = 0.f, a2 = 0.f, a3 = 0.f;
        #pragma unroll
        for (int ci = 0; ci < 3; ++ci)
          #pragma unroll
          for (int kh = 0; kh < 3; ++kh)
            #pragma unroll
            for (int kw = 0; kw < 3; ++kw) {
                int iw = ow*2 + kw - 1;
                float x = (iw >= 0 && iw < 128) ? simg[ci][2*os + kh][iw] : 0.f;
                float4 w4 = *reinterpret_cast<const float4*>(&wl[ci][kh*3 + kw][co4]);
                a0 += x*w4.x; a1 += x*w4.y; a2 += x*w4.z; a3 += x*w4.w;
            }
        float v0 = fmaxf(a0 + cbs[co4+0], 0.f);
        float v1 = fmaxf(a1 + cbs[co4+1], 0.f);
        float v2 = fmaxf(a2 + cbs[co4+2], 0.f);
        float v3 = fmaxf(a3 + cbs[co4+3], 0.f);
        yb[(size_t)(co4+0)*4096] = v0;
        yb[(size_t)(co4+1)*4096] = v1;
        yb[(size_t)(co4+2)*4096] = v2;
        yb[(size_t)(co4+3)*4096] = v3;
        float s0 = wsum(v0), q0 = wsum(v0*v0);
        float s1 = wsum(v1), q1 = wsum(v1*v1);
        float s2 = wsum(v2), q2 = wsum(v2*v2);
        float s3 = wsum(v3), q3 = wsum(v3*v3);
        if (ln == 0) {
            bs[wv][co4+0] += s0; bs2[wv][co4+0] += q0;
            bs[wv][co4+1] += s1; bs2[wv][co4+1] += q1;
            bs[wv][co4+2] += s2; bs2[wv][co4+2] += q2;
            bs[wv][co4+3] += s3; bs2[wv][co4+3] += q3;
        }
    }
    __syncthreads();
    if (tid < 24) {
        float S  = bs[0][tid] + bs[1][tid] + bs[2][tid] + bs[3][tid];
        float S2 = bs2[0][tid] + bs2[1][tid] + bs2[2][tid] + bs2[3][tid];
        atomicAdd(&bnp1[tid*2], S);
        atomicAdd(&bnp1[tid*2 + 1], S2);
    }
}

// ---------------------------------------------------------------- LSTM ----
__global__ void lstm_kernel(const int* __restrict__ qidx, const float* __restrict__ emb,
                            const float* __restrict__ WihT, const float* __restrict__ WhhT,
                            const float* __restrict__ bih, const float* __restrict__ bhh,
                            const float* __restrict__ h0, const float* __restrict__ c0,
                            float* __restrict__ qst)
{
    int b = blockIdx.x, tid = threadIdx.x;
    __shared__ float hs[128], cs[128], xs[32], gs[512];
    if (tid < 128) { hs[tid] = h0[b*128 + tid]; cs[tid] = c0[b*128 + tid]; }
    float bsum = bih[tid] + bhh[tid];
    for (int t = 0; t < 18; ++t) {
        if (tid < 32) {
            int id = qidx[b*18 + t];
            xs[tid] = (id != 0) ? emb[id*32 + tid] : 0.0f;
        }
        __syncthreads();
        float g = bsum;
        #pragma unroll
        for (int d = 0; d < 32; ++d) g += xs[d] * WihT[d*512 + tid];
        #pragma unroll 8
        for (int d = 0; d < 128; ++d) g += hs[d] * WhhT[d*512 + tid];
        gs[tid] = g;
        __syncthreads();
        if (tid < 128) {
            float ig = sigmoidf_(gs[tid]);
            float fg = sigmoidf_(gs[128 + tid]);
            float gg = tanhf(gs[256 + tid]);
            float og = sigmoidf_(gs[384 + tid]);
            float cn = fg * cs[tid] + ig * gg;
            cs[tid] = cn;
            hs[tid] = og * tanhf(cn);
        }
        __syncthreads();
    }
    if (tid < 128) qst[b*128 + tid] = cs[tid];   // final CELL state
}

// ------------------------------------------------------ conv2 (24->24) ----
__launch_bounds__(128, 4)
__global__ void conv2_kernel(const float* __restrict__ y1, const float* __restrict__ wk,
                             const float* __restrict__ cb,
                             const float* __restrict__ bnp, const float* __restrict__ gamma,
                             const float* __restrict__ beta,
                             float* __restrict__ y2, float* __restrict__ bnp2)
{
    __shared__ float sin2[24][5][64];
    __shared__ float wl[24][9][24];
    __shared__ float cbs[24];
    __shared__ float abs_[24], abo_[24];
    __shared__ float bss[24], bss2[24];
    int b = blockIdx.x, t = blockIdx.y, tid = threadIdx.x;
    BN_FOLD1(bnp, gamma, beta, 262144.f, abs_, abo_, tid);
    for (int i = tid; i < 5184; i += 128) {
        int co = i / 216, rem = i % 216;
        int ci = rem / 9, tap = rem % 9;
        wl[ci][tap][co] = wk[i];
    }
    if (tid < 24) cbs[tid] = cb[tid];
    __syncthreads();
    int base = 4*t - 1;
    for (int i = tid; i < 24*5*64; i += 128) {
        int ci = i / (5*64); int r2 = i % (5*64);
        int row = r2 / 64, colx = r2 % 64;
        int ih = base + row;
        sin2[ci][row][colx] = (ih >= 0 && ih < 64) ?
            y1[((size_t)(b*24 + ci)*64 + ih)*64 + colx] * abs_[ci] + abo_[ci] : 0.f;
    }
    __syncthreads();

    int pos = tid & 63;
    int ow = pos & 31, os = pos >> 5;
    int ch = tid >> 6;                       // wave id = co half
    int ln = tid & 63;
    int oh = 2*t + os;
    float acc[12];
    #pragma unroll
    for (int c = 0; c < 12; ++c) acc[c] = 0.f;

    for (int ci = 0; ci < 24; ++ci) {
        #pragma unroll
        for (int kh = 0; kh < 3; ++kh)
          #pragma unroll
          for (int kw = 0; kw < 3; ++kw) {
            int iw = ow*2 + kw - 1;
            float x = (iw >= 0 && iw < 64) ? sin2[ci][2*os + kh][iw] : 0.f;
            const float* wv = &wl[ci][kh*3 + kw][ch*12];
            #pragma unroll
            for (int c4 = 0; c4 < 3; ++c4) {
                float4 w4 = *reinterpret_cast<const float4*>(wv + c4*4);
                acc[c4*4+0] += x*w4.x;
                acc[c4*4+1] += x*w4.y;
                acc[c4*4+2] += x*w4.z;
                acc[c4*4+3] += x*w4.w;
            }
          }
    }
    #pragma unroll
    for (int c = 0; c < 12; ++c) {
        int co = ch*12 + c;
        float v = fmaxf(acc[c] + cbs[co], 0.f);
        y2[((size_t)(b*24 + co)*32 + oh)*32 + ow] = v;
        float s = wsum(v), q = wsum(v*v);
        if (ln == 0) { bss[co] = s; bss2[co] = q; }   // each co owned by 1 wave
    }
    __syncthreads();
    if (tid < 24) {
        atomicAdd(&bnp2[tid*2], bss[tid]);
        atomicAdd(&bnp2[tid*2 + 1], bss2[tid]);
    }
}

// ---------------------------------------------------------------- conv ----
// conv3/conv4 (BN of previous layer folded in-block; bn partials atomic-out)
__launch_bounds__(256, 2)
__global__ void conv_kernel(const float* __restrict__ in, const float* __restrict__ wk,
                            const float* __restrict__ cb,
                            const float* __restrict__ bnp, const float* __restrict__ gamma,
                            const float* __restrict__ beta, float Nprev,
                            float* __restrict__ out, float* __restrict__ bnp_out,
                            int Cin, int Hin, int Win, int Hout, int Wout)
{
    int cob = blockIdx.x;
    int co = cob % 24, b = cob / 24;
    int tid = threadIdx.x;
    __shared__ float sw[24*9];
    __shared__ float so9[9];
    __shared__ float bias;
    __shared__ float abs_[24], abo_[24];
    __shared__ float rs[256], rs2[256];
    BN_FOLD1(bnp, gamma, beta, Nprev, abs_, abo_, tid);
    __syncthreads();
    if (tid < Cin*9) {
        int ci = tid / 9, t = tid % 9;
        sw[tid] = wk[(co*Cin + ci)*9 + t] * abs_[ci];
    }
    if (tid < 9) {
        float s = 0.f;
        for (int ci = 0; ci < Cin; ++ci)
            s += abo_[ci] * wk[(co*Cin + ci)*9 + tid];
        so9[tid] = s;
    }
    if (tid == 0) bias = cb[co];
    __syncthreads();

    int HW = Hout * Wout;
    int pos = tid;
    float v = 0.f;
    if (pos < HW) {
        int ow = pos % Wout, oh = pos / Wout;
        float acc = bias;
        #pragma unroll
        for (int kh = 0; kh < 3; ++kh) {
            int ih = oh*2 + kh - 1;
            bool vh = (ih >= 0 && ih < Hin);
            #pragma unroll
            for (int kw = 0; kw < 3; ++kw) {
                int iw = ow*2 + kw - 1;
                if (vh && iw >= 0 && iw < Win) acc += so9[kh*3 + kw];
            }
        }
        const float* ipb = in + ((size_t)b * Cin) * Hin * Win;
        for (int ci = 0; ci < Cin; ++ci) {
            const float* ip = ipb + (size_t)ci * Hin * Win;
            const float* swp = sw + ci*9;
            #pragma unroll
            for (int kh = 0; kh < 3; ++kh) {
                int ih = oh*2 + kh - 1;
                if (ih < 0 || ih >= Hin) continue;
                #pragma unroll
                for (int kw = 0; kw < 3; ++kw) {
                    int iw = ow*2 + kw - 1;
                    if (iw < 0 || iw >= Win) continue;
                    acc += ip[ih*Win + iw] * swp[kh*3 + kw];
                }
            }
        }
        v = fmaxf(acc, 0.0f);
        out[((size_t)(b*24 + co)) * HW + pos] = v;
    }
    rs[tid] = v; rs2[tid] = v*v;
    __syncthreads();
    for (int st = 128; st > 0; st >>= 1) {
        if (tid < st) { rs[tid] += rs[tid + st]; rs2[tid] += rs2[tid + st]; }
        __syncthreads();
    }
    if (tid == 0) {
        atomicAdd(&bnp_out[co*2], rs[0]);
        atomicAdd(&bnp_out[co*2 + 1], rs2[0]);
    }
}

// ------------------------------------- xf + first g-layer decomposition ---
__global__ void aiajq_kernel(const float* __restrict__ y4,
                             const float* __restrict__ bnp, const float* __restrict__ gamma,
                             const float* __restrict__ beta,
                             const float* __restrict__ qst,
                             const float* __restrict__ Wg1, const float* __restrict__ bg1,
                             float* __restrict__ Ai, float* __restrict__ Aj, float* __restrict__ Q)
{
    int b = blockIdx.x, c = threadIdx.x;          // 64 x 256
    __shared__ float xfl[64 * 26];
    __shared__ float qv[128];
    __shared__ float abs_[24], abo_[24];
    BN_FOLD1(bnp, gamma, beta, 4096.f, abs_, abo_, c);
    __syncthreads();
    for (int i = c; i < 64*24; i += 256) {
        int p = i / 24, ch = i % 24;
        xfl[p*26 + ch] = y4[((size_t)(b*24 + ch)) * 64 + p] * abs_[ch] + abo_[ch];
    }
    if (c < 64) {
        xfl[c*26 + 24] = ((float)c / 8.0f - 4.0f) * 0.25f;   // python true division i/D
        xfl[c*26 + 25] = ((float)(c % 8) - 4.0f) * 0.25f;    // integer i%D
    }
    if (c < 128) qv[c] = qst[b*128 + c];
    __syncthreads();
    const float* w = Wg1 + (size_t)c * 180;
    float wa[26], wb[26];
    #pragma unroll
    for (int d = 0; d < 26; ++d) { wa[d] = w[d]; wb[d] = w[26 + d]; }
    float q = bg1[c];
    for (int d = 0; d < 128; ++d) q += qv[d] * w[52 + d];
    Q[b*256 + c] = q;
    for (int j = 0; j < 64; ++j) {
        const float* xr = xfl + j*26;
        float sa = 0.f, sb = 0.f;
        #pragma unroll
        for (int d = 0; d < 26; ++d) { sa += xr[d]*wa[d]; sb += xr[d]*wb[d]; }
        Ai[((size_t)(b*64 + j))*256 + c] = sa;
        Aj[((size_t)(b*64 + j))*256 + c] = sb;
    }
}

// --------------------------------------------------------------- g-MLP ----
// explicit depth-1 prefetch of B (L2-latency) and A (LDS) fragments:
// R11 VGPR=52 of 128 cap showed the compiler wasn't hoisting loads.
__launch_bounds__(512, 4)
__global__ void gmlp_kernel(const float* __restrict__ Ai, const float* __restrict__ Aj,
                            const float* __restrict__ Q,
                            const unsigned short* __restrict__ Wt2, const float* __restrict__ bg2,
                            const unsigned short* __restrict__ Wt3, const float* __restrict__ bg3,
                            const unsigned short* __restrict__ Wt4, const float* __restrict__ bg4,
                            float* __restrict__ partial)
{
    constexpr int LDP = 264;
    __shared__ __align__(16) unsigned short buf[128 * LDP];   // 67584 B
    int tid = threadIdx.x;
    int blk = blockIdx.x;                   // 2048 = 64 b x 32 k-pairs
    int b = blk >> 5;
    int k0 = (blk & 31) << 1;

    {
        int g  = tid >> 8;
        int jh = (tid >> 7) & 1;
        int c2 = tid & 127;
        float2 aj = *((const float2*)(Aj + ((size_t)(b*64 + k0 + g))*256) + c2);
        float2 qq = *((const float2*)(Q + b*256) + c2);
        float a0 = aj.x + qq.x, a1 = aj.y + qq.y;
        const float2* aip = (const float2*)(Ai + ((size_t)b*64)*256) + c2;
        #pragma unroll 4
        for (int j = jh*32; j < jh*32 + 32; ++j) {
            float2 av = aip[(size_t)j*128];
            unsigned lo = f2bfh(fmaxf(av.x + a0, 0.f));
            unsigned hv = f2bfh(fmaxf(av.y + a1, 0.f));
            *(unsigned*)(&buf[(size_t)(g*64 + j)*LDP + 2*c2]) = lo | (hv << 16);
        }
    }
    __syncthreads();

    int l = tid & 63, w = tid >> 6;
    int rh = w >> 2;
    int cg = w & 3;
    int lid = l & 31, hi = l >> 5;
    int arow = rh*64 + lid;
    int colA = cg*64 + lid;
    int colB = colA + 32;

    const unsigned short* Ws[3] = {Wt2, Wt3, Wt4};
    const float* Bs[3] = {bg2, bg3, bg4};

    #pragma unroll
    for (int layer = 0; layer < 3; ++layer) {
        const unsigned short* W = Ws[layer];
        const float* bias = Bs[layer];
        f32x16 acc00, acc01, acc10, acc11;
        #pragma unroll
        for (int i = 0; i < 16; ++i) { acc00[i]=0.f; acc01[i]=0.f; acc10[i]=0.f; acc11[i]=0.f; }

        const unsigned short* wp0 = W + (size_t)hi*2048 + colA*8;
        const unsigned short* wp1 = W + (size_t)hi*2048 + colB*8;
        const unsigned short* ap  = buf + arow*LDP + hi*8;

        bf16x8 nb0 = *reinterpret_cast<const bf16x8*>(wp0);
        bf16x8 nb1 = *reinterpret_cast<const bf16x8*>(wp1);
        bf16x8 na0 = *reinterpret_cast<const bf16x8*>(ap);
        bf16x8 na1 = *reinterpret_cast<const bf16x8*>(ap + 32*LDP);
        #pragma unroll
        for (int kk = 0; kk < 16; ++kk) {
            bf16x8 b0 = nb0, b1 = nb1, a0 = na0, a1 = na1;
            if (kk < 15) {
                nb0 = *reinterpret_cast<const bf16x8*>(wp0 + (kk+1)*4096);
                nb1 = *reinterpret_cast<const bf16x8*>(wp1 + (kk+1)*4096);
                na0 = *reinterpret_cast<const bf16x8*>(ap + (kk+1)*16);
                na1 = *reinterpret_cast<const bf16x8*>(ap + 32*LDP + (kk+1)*16);
            }
            acc00 = __builtin_amdgcn_mfma_f32_32x32x16_bf16(a0, b0, acc00, 0, 0, 0);
            acc01 = __builtin_amdgcn_mfma_f32_32x32x16_bf16(a0, b1, acc01, 0, 0, 0);
            acc10 = __builtin_amdgcn_mfma_f32_32x32x16_bf16(a1, b0, acc10, 0, 0, 0);
            acc11 = __builtin_amdgcn_mfma_f32_32x32x16_bf16(a1, b1, acc11, 0, 0, 0);
        }

        if (layer < 2) {
            float bc0 = bias[colA], bc1 = bias[colB];
            __syncthreads();
            #pragma unroll
            for (int reg = 0; reg < 16; ++reg) {
                int r0 = rh*64 + (reg & 3) + 8*(reg >> 2) + 4*hi;
                buf[r0*LDP + colA] = f2bfh(fmaxf(acc00[reg] + bc0, 0.f));
                buf[r0*LDP + colB] = f2bfh(fmaxf(acc01[reg] + bc1, 0.f));
                int r1 = r0 + 32;
                buf[r1*LDP + colA] = f2bfh(fmaxf(acc10[reg] + bc0, 0.f));
                buf[r1*LDP + colB] = f2bfh(fmaxf(acc11[reg] + bc1, 0.f));
            }
            __syncthreads();
        } else {
            float bc0 = bias[colA], bc1 = bias[colB];
            float cs0 = 0.f, cs1 = 0.f;
            #pragma unroll
            for (int reg = 0; reg < 16; ++reg) {
                cs0 += fmaxf(acc00[reg] + bc0, 0.f) + fmaxf(acc10[reg] + bc0, 0.f);
                cs1 += fmaxf(acc01[reg] + bc1, 0.f) + fmaxf(acc11[reg] + bc1, 0.f);
            }
            cs0 += __shfl_xor(cs0, 32);
            cs1 += __shfl_xor(cs1, 32);
            if (hi == 0) {
                float* pp = partial + ((size_t)blk*2 + rh)*256;
                pp[colA] = cs0;
                pp[colB] = cs1;
            }
        }
    }
}

// ---------------------------------------- partial-reduce + f-MLP fused ----
__global__ void fmlp_kernel(const float* __restrict__ partial,
                            const float* __restrict__ Wf1, const float* __restrict__ bf1,
                            const float* __restrict__ Wf2, const float* __restrict__ bf2,
                            const float* __restrict__ Wf3, const float* __restrict__ bf3,
                            float* __restrict__ out)
{
    int b = blockIdx.x, tid = threadIdx.x;
    __shared__ float v0[256], v1[256], lgt[28];
    {
        float s0 = 0.f, s1 = 0.f, s2 = 0.f, s3 = 0.f;
        const float* p = partial + ((size_t)b * 64) * 256 + tid;
        #pragma unroll
        for (int k = 0; k < 64; k += 4) {
            s0 += p[(size_t)(k+0) * 256];
            s1 += p[(size_t)(k+1) * 256];
            s2 += p[(size_t)(k+2) * 256];
            s3 += p[(size_t)(k+3) * 256];
        }
        v0[tid] = (s0 + s1) + (s2 + s3);
    }
    __syncthreads();
    {
        float s = bf1[tid];
        const float4* wr = reinterpret_cast<const float4*>(Wf1 + (size_t)tid * 256);
        for (int k4 = 0; k4 < 64; ++k4) {
            float4 wv = wr[k4];
            s += wv.x*v0[k4*4+0] + wv.y*v0[k4*4+1] + wv.z*v0[k4*4+2] + wv.w*v0[k4*4+3];
        }
        v1[tid] = fmaxf(s, 0.f);
    }
    __syncthreads();
    {
        float s = bf2[tid];
        const float4* wr = reinterpret_cast<const float4*>(Wf2 + (size_t)tid * 256);
        for (int k4 = 0; k4 < 64; ++k4) {
            float4 wv = wr[k4];
            s += wv.x*v1[k4*4+0] + wv.y*v1[k4*4+1] + wv.z*v1[k4*4+2] + wv.w*v1[k4*4+3];
        }
        v0[tid] = fmaxf(s, 0.f);
    }
    __syncthreads();
    if (tid < 28) {
        float s = bf3[tid];
        const float4* wr = reinterpret_cast<const float4*>(Wf3 + (size_t)tid * 256);
        for (int k4 = 0; k4 < 64; ++k4) {
            float4 wv = wr[k4];
            s += wv.x*v0[k4*4+0] + wv.y*v0[k4*4+1] + wv.z*v0[k4*4+2] + wv.w*v0[k4*4+3];
        }
        lgt[tid] = s;
    }
    __syncthreads();
    if (tid == 0) {
        float mx = -1e30f;
        for (int i = 0; i < 28; ++i) mx = fmaxf(mx, lgt[i]);
        float se = 0.f;
        for (int i = 0; i < 28; ++i) se += expf(lgt[i] - mx);
        float lse = mx + logf(se);
        for (int i = 0; i < 28; ++i) out[b*28 + i] = lgt[i] - lse;
    }
}

// ------------------------------------------------------------- launch -----
extern "C" void kernel_launch(void* const* d_in, const int* in_sizes, int n_in,
                              void* d_out, int out_size, void* d_ws, size_t ws_size,
                              hipStream_t stream)
{
    (void)in_sizes; (void)n_in; (void)out_size; (void)ws_size;
    const float* img = (const float*)d_in[0];
    const int*   qidx= (const int*)  d_in[1];
    const float* emb = (const float*)d_in[2];
    const float* Wih = (const float*)d_in[3];
    const float* Whh = (const float*)d_in[4];
    const float* bih = (const float*)d_in[5];
    const float* bhh = (const float*)d_in[6];
    const float* k1  = (const float*)d_in[7];  const float* cb1=(const float*)d_in[8];
    const float* g1  = (const float*)d_in[9];  const float* be1=(const float*)d_in[10];
    const float* k2  = (const float*)d_in[11]; const float* cb2=(const float*)d_in[12];
    const float* g2  = (const float*)d_in[13]; const float* be2=(const float*)d_in[14];
    const float* k3  = (const float*)d_in[15]; const float* cb3=(const float*)d_in[16];
    const float* g3  = (const float*)d_in[17]; const float* be3=(const float*)d_in[18];
    const float* k4  = (const float*)d_in[19]; const float* cb4=(const float*)d_in[20];
    const float* g4  = (const float*)d_in[21]; const float* be4=(const float*)d_in[22];
    const float* Wg1 = (const float*)d_in[23]; const float* bg1=(const float*)d_in[24];
    const float* Wg2 = (const float*)d_in[25]; const float* bg2=(const float*)d_in[26];
    const float* Wg3 = (const float*)d_in[27]; const float* bg3=(const float*)d_in[28];
    const float* Wg4 = (const float*)d_in[29]; const float* bg4=(const float*)d_in[30];
    const float* Wf1 = (const float*)d_in[31]; const float* bf1=(const float*)d_in[32];
    const float* Wf2 = (const float*)d_in[33]; const float* bf2=(const float*)d_in[34];
    const float* Wf3 = (const float*)d_in[35]; const float* bf3=(const float*)d_in[36];
    const float* h0  = (const float*)d_in[37]; const float* c0 =(const float*)d_in[38];
    float* out = (float*)d_out;

    // workspace carve-up (floats), all 16B aligned
    float* ws = (float*)d_ws;
    float* y1 = ws;   ws += 64*24*64*64;
    float* y2 = ws;   ws += 64*24*32*32;
    float* y3 = ws;   ws += 64*24*16*16;
    float* y4 = ws;   ws += 64*24*8*8;
    float* bnp = ws;  ws += 192;           // bnp1..4, 48 floats each
    float* bnp1 = bnp, *bnp2 = bnp + 48, *bnp3 = bnp + 96, *bnp4 = bnp + 144;
    float* qst = ws;  ws += 64*128;
    float* Ai  = ws;  ws += 64*64*256;
    float* Aj  = ws;  ws += 64*64*256;
    float* Qb  = ws;  ws += 64*256;
    unsigned short* Wt2 = (unsigned short*)ws; ws += 65536/2;
    unsigned short* Wt3 = (unsigned short*)ws; ws += 65536/2;
    unsigned short* Wt4 = (unsigned short*)ws; ws += 65536/2;
    float* WihT = ws; ws += 32*512;
    float* WhhT = ws; ws += 128*512;
    float* partial = ws; ws += 2048*2*256;

    hipMemsetAsync(bnp, 0, 192*sizeof(float), stream);

    prep_conv1_kernel<<<2112, 256, 0, stream>>>(img, k1, cb1, y1, bnp1,
                                                Wg2, Wg3, Wg4, Wih, Whh,
                                                Wt2, Wt3, Wt4, WihT, WhhT);
    lstm_kernel<<<64, 512, 0, stream>>>(qidx, emb, WihT, WhhT, bih, bhh, h0, c0, qst);

    conv2_kernel<<<dim3(64, 16), 128, 0, stream>>>(y1, k2, cb2, bnp1, g1, be1, y2, bnp2);
    conv_kernel<<<1536, 256, 0, stream>>>(y2, k3, cb3, bnp2, g2, be2, 65536.f,
                                          y3, bnp3, 24, 32, 32, 16, 16);
    conv_kernel<<<1536, 256, 0, stream>>>(y3, k4, cb4, bnp3, g3, be3, 16384.f,
                                          y4, bnp4, 24, 16, 16, 8, 8);

    aiajq_kernel<<<64, 256, 0, stream>>>(y4, bnp4, g4, be4, qst, Wg1, bg1, Ai, Aj, Qb);

    gmlp_kernel<<<2048, 512, 0, stream>>>(Ai, Aj, Qb, Wt2, bg2, Wt3, bg3, Wt4, bg4, partial);
    fmlp_kernel<<<64, 256, 0, stream>>>(partial, Wf1, bf1, Wf2, bf2, Wf3, bf3, out);
}

// Round 13
// 455.517 us; speedup vs baseline: 1.1093x; 1.1093x over previous
//
#include <hip/hip_runtime.h>
#include <math.h>

typedef __bf16 bf16x8 __attribute__((ext_vector_type(8)));
typedef float  f32x16 __attribute__((ext_vector_type(16)));

#define DEVFN __device__ __forceinline__

DEVFN unsigned short f2bfh(float f) {
    __bf16 h = (__bf16)f;
    union { __bf16 h; unsigned short u; } v; v.h = h;
    return v.u;
}
DEVFN float sigmoidf_(float x) { return 1.0f / (1.0f + expf(-x)); }

// ---------------- weight prep: Wg->bf16 transposed, Wih/Whh -> [d][row] ----
__global__ void cvt_kernel(const float* __restrict__ Wg2, const float* __restrict__ Wg3,
                           const float* __restrict__ Wg4,
                           const float* __restrict__ Wih, const float* __restrict__ Whh,
                           unsigned short* __restrict__ Wt2, unsigned short* __restrict__ Wt3,
                           unsigned short* __restrict__ Wt4,
                           float* __restrict__ WihT, float* __restrict__ WhhT)
{
    int i = blockIdx.x * 512 + threadIdx.x;
    if (i < 196608) {                                  // Wg2/3/4 -> bf16 [k/8][col][8]
        int seg = i >> 16, idx = i & 65535;
        const float* src = (seg == 0) ? Wg2 : (seg == 1) ? Wg3 : Wg4;
        unsigned short* dst = (seg == 0) ? Wt2 : (seg == 1) ? Wt3 : Wt4;
        int col = idx >> 8, k = idx & 255;
        dst[(k >> 3)*2048 + col*8 + (k & 7)] = f2bfh(src[idx]);
    } else {
        int j = i - 196608;
        if (j < 65536) {                               // WhhT[d][row], coalesced write
            int d = j >> 9, row = j & 511;
            WhhT[j] = Whh[row*128 + d];
        } else if (j < 81920) {
            j -= 65536;                                // WihT[d][row]
            int d = j >> 9, row = j & 511;
            WihT[j] = Wih[row*32 + d];
        }
    }
}

// ---------------------------------------------------------------- LSTM ----
// transposed weights: lane-contiguous loads (R10 lesson: Whh[tid*128+d]
// row-major reads were heavily uncoalesced L2 line traffic).
__global__ void lstm_kernel(const int* __restrict__ qidx, const float* __restrict__ emb,
                            const float* __restrict__ WihT, const float* __restrict__ WhhT,
                            const float* __restrict__ bih, const float* __restrict__ bhh,
                            const float* __restrict__ h0, const float* __restrict__ c0,
                            float* __restrict__ qst)
{
    int b = blockIdx.x, tid = threadIdx.x;
    __shared__ float hs[128], cs[128], xs[32], gs[512];
    if (tid < 128) { hs[tid] = h0[b*128 + tid]; cs[tid] = c0[b*128 + tid]; }
    float bsum = bih[tid] + bhh[tid];
    for (int t = 0; t < 18; ++t) {
        if (tid < 32) {
            int id = qidx[b*18 + t];
            xs[tid] = (id != 0) ? emb[id*32 + tid] : 0.0f;
        }
        __syncthreads();
        float g = bsum;
        #pragma unroll
        for (int d = 0; d < 32; ++d) g += xs[d] * WihT[d*512 + tid];
        #pragma unroll 8
        for (int d = 0; d < 128; ++d) g += hs[d] * WhhT[d*512 + tid];
        gs[tid] = g;
        __syncthreads();
        if (tid < 128) {
            float ig = sigmoidf_(gs[tid]);
            float fg = sigmoidf_(gs[128 + tid]);
            float gg = tanhf(gs[256 + tid]);
            float og = sigmoidf_(gs[384 + tid]);
            float cn = fg * cs[tid] + ig * gg;
            cs[tid] = cn;
            hs[tid] = og * tanhf(cn);
        }
        __syncthreads();
    }
    if (tid < 128) qst[b*128 + tid] = cs[tid];   // final CELL state
}

// ------------------------------------------------------- conv1 (3->24) ----
// R5/R7/R8 lesson: ANY per-thread accumulator array live across the tap
// loop gets spilled by this compiler. 4 NAMED scalars per co-group.
__launch_bounds__(256, 4)
__global__ void conv1_kernel(const float* __restrict__ img, const float* __restrict__ wk,
                             const float* __restrict__ cb, float* __restrict__ y1)
{
    __shared__ float simg[3][9][128];
    __shared__ __align__(16) float wl[3][9][24];
    __shared__ float cbs[24];
    int b = blockIdx.x, t = blockIdx.y, tid = threadIdx.x;
    for (int i = tid; i < 648; i += 256) {
        int co = i / 27, rem = i % 27;
        wl[rem / 9][rem % 9][co] = wk[i];
    }
    if (tid < 24) cbs[tid] = cb[tid];
    int base = 8*t - 1;
    for (int i = tid; i < 3*9*128; i += 256) {
        int ci = i / (9*128); int r2 = i % (9*128);
        int row = r2 / 128, colx = r2 % 128;
        int ih = base + row;
        simg[ci][row][colx] = (ih >= 0 && ih < 128) ?
            img[((size_t)(b*3 + ci)*128 + ih)*128 + colx] : 0.f;
    }
    __syncthreads();

    int ow = tid & 63;
    int os = tid >> 6;
    int oh = t*4 + os;
    float* yb = y1 + ((size_t)b*24*64 + oh)*64 + ow;

    #pragma unroll
    for (int co4 = 0; co4 < 24; co4 += 4) {
        float a0 = 0.f, a1 = 0.f, a2 = 0.f, a3 = 0.f;
        #pragma unroll
        for (int ci = 0; ci < 3; ++ci)
          #pragma unroll
          for (int kh = 0; kh < 3; ++kh)
            #pragma unroll
            for (int kw = 0; kw < 3; ++kw) {
                int iw = ow*2 + kw - 1;
                float x = (iw >= 0 && iw < 128) ? simg[ci][2*os + kh][iw] : 0.f;
                float4 w4 = *reinterpret_cast<const float4*>(&wl[ci][kh*3 + kw][co4]);
                a0 += x*w4.x; a1 += x*w4.y; a2 += x*w4.z; a3 += x*w4.w;
            }
        yb[(size_t)(co4+0)*4096] = fmaxf(a0 + cbs[co4+0], 0.f);
        yb[(size_t)(co4+1)*4096] = fmaxf(a1 + cbs[co4+1], 0.f);
        yb[(size_t)(co4+2)*4096] = fmaxf(a2 + cbs[co4+2], 0.f);
        yb[(size_t)(co4+3)*4096] = fmaxf(a3 + cbs[co4+3], 0.f);
    }
}

// ---- BN partial stats (stage 1); finalization folded into consumers ------
__global__ void bn_partial_kernel(const float* __restrict__ y, float* __restrict__ part,
                                  int HW, int nb)
{
    int c = blockIdx.x;
    int s = blockIdx.y;
    int S = gridDim.y;
    int tid = threadIdx.x;
    int n4 = HW >> 2;
    float sum = 0.f, sum2 = 0.f;
    for (int b = s * nb; b < (s + 1) * nb; ++b) {
        const float4* p = reinterpret_cast<const float4*>(y + ((size_t)(b*24 + c)) * HW);
        for (int i = tid; i < n4; i += 256) {
            float4 v = p[i];
            sum  += v.x + v.y + v.z + v.w;
            sum2 += v.x*v.x + v.y*v.y + v.z*v.z + v.w*v.w;
        }
    }
    __shared__ float rs[256], rs2[256];
    rs[tid] = sum; rs2[tid] = sum2;
    __syncthreads();
    for (int st = 128; st > 0; st >>= 1) {
        if (tid < st) { rs[tid] += rs[tid + st]; rs2[tid] += rs2[tid + st]; }
        __syncthreads();
    }
    if (tid == 0) {
        part[(c * S + s) * 2]     = rs[0];
        part[(c * S + s) * 2 + 1] = rs2[0];
    }
}

// shared helper: fold bnp -> per-channel scale/offset in LDS
#define BN_FOLD(bnp, gamma, beta, S, N, abs_, abo_, tid)                    \
    if (tid < 24) {                                                          \
        float s_ = 0.f, s2_ = 0.f;                                           \
        for (int i_ = 0; i_ < (S); ++i_) {                                   \
            s_  += (bnp)[((tid)*(S) + i_)*2];                                \
            s2_ += (bnp)[((tid)*(S) + i_)*2 + 1];                            \
        }                                                                    \
        float m_ = s_ / (N);                                                 \
        float v_ = s2_ / (N) - m_*m_;                                        \
        float r_ = rsqrtf(v_ + 1e-5f);                                       \
        float a_ = (gamma)[tid] * r_;                                        \
        (abs_)[tid] = a_; (abo_)[tid] = (beta)[tid] - m_*a_;                 \
    }

// ------------------------------------------------------ conv2 (24->24) ----
__launch_bounds__(128, 4)
__global__ void conv2_kernel(const float* __restrict__ y1, const float* __restrict__ wk,
                             const float* __restrict__ cb,
                             const float* __restrict__ bnp, const float* __restrict__ gamma,
                             const float* __restrict__ beta,
                             float* __restrict__ y2)
{
    __shared__ float sin2[24][5][64];
    __shared__ float wl[24][9][24];
    __shared__ float cbs[24];
    __shared__ float abs_[24], abo_[24];
    int b = blockIdx.x, t = blockIdx.y, tid = threadIdx.x;
    BN_FOLD(bnp, gamma, beta, 16, 262144, abs_, abo_, tid);
    for (int i = tid; i < 5184; i += 128) {
        int co = i / 216, rem = i % 216;
        int ci = rem / 9, tap = rem % 9;
        wl[ci][tap][co] = wk[i];
    }
    if (tid < 24) cbs[tid] = cb[tid];
    __syncthreads();
    int base = 4*t - 1;
    for (int i = tid; i < 24*5*64; i += 128) {
        int ci = i / (5*64); int r2 = i % (5*64);
        int row = r2 / 64, colx = r2 % 64;
        int ih = base + row;
        sin2[ci][row][colx] = (ih >= 0 && ih < 64) ?
            y1[((size_t)(b*24 + ci)*64 + ih)*64 + colx] * abs_[ci] + abo_[ci] : 0.f;
    }
    __syncthreads();

    int pos = tid & 63;
    int ow = pos & 31, os = pos >> 5;
    int ch = tid >> 6;
    int oh = 2*t + os;
    float acc[12];
    #pragma unroll
    for (int c = 0; c < 12; ++c) acc[c] = 0.f;

    for (int ci = 0; ci < 24; ++ci) {
        #pragma unroll
        for (int kh = 0; kh < 3; ++kh)
          #pragma unroll
          for (int kw = 0; kw < 3; ++kw) {
            int iw = ow*2 + kw - 1;
            float x = (iw >= 0 && iw < 64) ? sin2[ci][2*os + kh][iw] : 0.f;
            const float* wv = &wl[ci][kh*3 + kw][ch*12];
            #pragma unroll
            for (int c4 = 0; c4 < 3; ++c4) {
                float4 w4 = *reinterpret_cast<const float4*>(wv + c4*4);
                acc[c4*4+0] += x*w4.x;
                acc[c4*4+1] += x*w4.y;
                acc[c4*4+2] += x*w4.z;
                acc[c4*4+3] += x*w4.w;
            }
          }
    }
    #pragma unroll
    for (int c = 0; c < 12; ++c) {
        int co = ch*12 + c;
        y2[((size_t)(b*24 + co)*32 + oh)*32 + ow] = fmaxf(acc[c] + cbs[co], 0.f);
    }
}

// ---------------------------------------------------------------- conv ----
__launch_bounds__(256, 2)
__global__ void conv_kernel(const float* __restrict__ in, const float* __restrict__ wk,
                            const float* __restrict__ cb,
                            const float* __restrict__ bnp, const float* __restrict__ gamma,
                            const float* __restrict__ beta, int S, int N,
                            float* __restrict__ out,
                            int Cin, int Hin, int Win, int Hout, int Wout)
{
    int cob = blockIdx.x;
    int co = cob % 24, b = cob / 24;
    int tid = threadIdx.x;
    __shared__ float sw[24*9];
    __shared__ float so9[9];
    __shared__ float bias;
    __shared__ float abs_[24], abo_[24];
    BN_FOLD(bnp, gamma, beta, S, N, abs_, abo_, tid);
    __syncthreads();
    if (tid < Cin*9) {
        int ci = tid / 9, t = tid % 9;
        sw[tid] = wk[(co*Cin + ci)*9 + t] * abs_[ci];
    }
    if (tid < 9) {
        float s = 0.f;
        for (int ci = 0; ci < Cin; ++ci)
            s += abo_[ci] * wk[(co*Cin + ci)*9 + tid];
        so9[tid] = s;
    }
    if (tid == 0) bias = cb[co];
    __syncthreads();

    int HW = Hout * Wout;
    int pos = tid;
    if (pos >= HW) return;
    int ow = pos % Wout, oh = pos / Wout;

    float acc = bias;
    #pragma unroll
    for (int kh = 0; kh < 3; ++kh) {
        int ih = oh*2 + kh - 1;
        bool vh = (ih >= 0 && ih < Hin);
        #pragma unroll
        for (int kw = 0; kw < 3; ++kw) {
            int iw = ow*2 + kw - 1;
            if (vh && iw >= 0 && iw < Win) acc += so9[kh*3 + kw];
        }
    }
    const float* ipb = in + ((size_t)b * Cin) * Hin * Win;
    for (int ci = 0; ci < Cin; ++ci) {
        const float* ip = ipb + (size_t)ci * Hin * Win;
        const float* swp = sw + ci*9;
        #pragma unroll
        for (int kh = 0; kh < 3; ++kh) {
            int ih = oh*2 + kh - 1;
            if (ih < 0 || ih >= Hin) continue;
            #pragma unroll
            for (int kw = 0; kw < 3; ++kw) {
                int iw = ow*2 + kw - 1;
                if (iw < 0 || iw >= Win) continue;
                acc += ip[ih*Win + iw] * swp[kh*3 + kw];
            }
        }
    }
    out[((size_t)(b*24 + co)) * HW + pos] = fmaxf(acc, 0.0f);
}

// ------------------------------------- xf + first g-layer decomposition ---
__global__ void aiajq_kernel(const float* __restrict__ y4,
                             const float* __restrict__ bnp, const float* __restrict__ gamma,
                             const float* __restrict__ beta,
                             const float* __restrict__ qst,
                             const float* __restrict__ Wg1, const float* __restrict__ bg1,
                             float* __restrict__ Ai, float* __restrict__ Aj, float* __restrict__ Q)
{
    int b = blockIdx.x, c = threadIdx.x;          // 64 x 256
    __shared__ float xfl[64 * 26];
    __shared__ float qv[128];
    __shared__ float abs_[24], abo_[24];
    BN_FOLD(bnp, gamma, beta, 1, 4096, abs_, abo_, c);
    __syncthreads();
    for (int i = c; i < 64*24; i += 256) {
        int p = i / 24, ch = i % 24;
        xfl[p*26 + ch] = y4[((size_t)(b*24 + ch)) * 64 + p] * abs_[ch] + abo_[ch];
    }
    if (c < 64) {
        xfl[c*26 + 24] = ((float)c / 8.0f - 4.0f) * 0.25f;   // python true division i/D
        xfl[c*26 + 25] = ((float)(c % 8) - 4.0f) * 0.25f;    // integer i%D
    }
    if (c < 128) qv[c] = qst[b*128 + c];
    __syncthreads();
    const float* w = Wg1 + (size_t)c * 180;
    float wa[26], wb[26];
    #pragma unroll
    for (int d = 0; d < 26; ++d) { wa[d] = w[d]; wb[d] = w[26 + d]; }
    float q = bg1[c];
    for (int d = 0; d < 128; ++d) q += qv[d] * w[52 + d];
    Q[b*256 + c] = q;
    for (int j = 0; j < 64; ++j) {
        const float* xr = xfl + j*26;
        float sa = 0.f, sb = 0.f;
        #pragma unroll
        for (int d = 0; d < 26; ++d) { sa += xr[d]*wa[d]; sb += xr[d]*wb[d]; }
        Ai[((size_t)(b*64 + j))*256 + c] = sa;
        Aj[((size_t)(b*64 + j))*256 + c] = sb;
    }
}

// --------------------------------------------------------------- g-MLP ----
__launch_bounds__(512, 4)
__global__ void gmlp_kernel(const float* __restrict__ Ai, const float* __restrict__ Aj,
                            const float* __restrict__ Q,
                            const unsigned short* __restrict__ Wt2, const float* __restrict__ bg2,
                            const unsigned short* __restrict__ Wt3, const float* __restrict__ bg3,
                            const unsigned short* __restrict__ Wt4, const float* __restrict__ bg4,
                            float* __restrict__ partial)
{
    constexpr int LDP = 264;
    __shared__ __align__(16) unsigned short buf[128 * LDP];   // 67584 B
    int tid = threadIdx.x;
    int blk = blockIdx.x;                   // 2048 = 64 b x 32 k-pairs
    int b = blk >> 5;
    int k0 = (blk & 31) << 1;

    {
        int g  = tid >> 8;
        int jh = (tid >> 7) & 1;
        int c2 = tid & 127;
        float2 aj = *((const float2*)(Aj + ((size_t)(b*64 + k0 + g))*256) + c2);
        float2 qq = *((const float2*)(Q + b*256) + c2);
        float a0 = aj.x + qq.x, a1 = aj.y + qq.y;
        const float2* aip = (const float2*)(Ai + ((size_t)b*64)*256) + c2;
        #pragma unroll 4
        for (int j = jh*32; j < jh*32 + 32; ++j) {
            float2 av = aip[(size_t)j*128];
            unsigned lo = f2bfh(fmaxf(av.x + a0, 0.f));
            unsigned hv = f2bfh(fmaxf(av.y + a1, 0.f));
            *(unsigned*)(&buf[(size_t)(g*64 + j)*LDP + 2*c2]) = lo | (hv << 16);
        }
    }
    __syncthreads();

    int l = tid & 63, w = tid >> 6;
    int rh = w >> 2;
    int cg = w & 3;
    int lid = l & 31, hi = l >> 5;
    int arow = rh*64 + lid;
    int colA = cg*64 + lid;
    int colB = colA + 32;

    const unsigned short* Ws[3] = {Wt2, Wt3, Wt4};
    const float* Bs[3] = {bg2, bg3, bg4};

    #pragma unroll
    for (int layer = 0; layer < 3; ++layer) {
        const unsigned short* W = Ws[layer];
        const float* bias = Bs[layer];
        f32x16 acc00, acc01, acc10, acc11;
        #pragma unroll
        for (int i = 0; i < 16; ++i) { acc00[i]=0.f; acc01[i]=0.f; acc10[i]=0.f; acc11[i]=0.f; }

        const unsigned short* wp0 = W + (size_t)hi*2048 + colA*8;
        const unsigned short* wp1 = W + (size_t)hi*2048 + colB*8;
        const unsigned short* ap  = buf + arow*LDP + hi*8;

        #pragma unroll
        for (int kk = 0; kk < 16; ++kk) {
            bf16x8 b0 = *reinterpret_cast<const bf16x8*>(wp0 + kk*4096);
            bf16x8 b1 = *reinterpret_cast<const bf16x8*>(wp1 + kk*4096);
            bf16x8 a0 = *reinterpret_cast<const bf16x8*>(ap + kk*16);
            bf16x8 a1 = *reinterpret_cast<const bf16x8*>(ap + 32*LDP + kk*16);
            acc00 = __builtin_amdgcn_mfma_f32_32x32x16_bf16(a0, b0, acc00, 0, 0, 0);
            acc01 = __builtin_amdgcn_mfma_f32_32x32x16_bf16(a0, b1, acc01, 0, 0, 0);
            acc10 = __builtin_amdgcn_mfma_f32_32x32x16_bf16(a1, b0, acc10, 0, 0, 0);
            acc11 = __builtin_amdgcn_mfma_f32_32x32x16_bf16(a1, b1, acc11, 0, 0, 0);
        }

        if (layer < 2) {
            float bc0 = bias[colA], bc1 = bias[colB];
            __syncthreads();
            #pragma unroll
            for (int reg = 0; reg < 16; ++reg) {
                int r0 = rh*64 + (reg & 3) + 8*(reg >> 2) + 4*hi;
                buf[r0*LDP + colA] = f2bfh(fmaxf(acc00[reg] + bc0, 0.f));
                buf[r0*LDP + colB] = f2bfh(fmaxf(acc01[reg] + bc1, 0.f));
                int r1 = r0 + 32;
                buf[r1*LDP + colA] = f2bfh(fmaxf(acc10[reg] + bc0, 0.f));
                buf[r1*LDP + colB] = f2bfh(fmaxf(acc11[reg] + bc1, 0.f));
            }
            __syncthreads();
        } else {
            float bc0 = bias[colA], bc1 = bias[colB];
            float cs0 = 0.f, cs1 = 0.f;
            #pragma unroll
            for (int reg = 0; reg < 16; ++reg) {
                cs0 += fmaxf(acc00[reg] + bc0, 0.f) + fmaxf(acc10[reg] + bc0, 0.f);
                cs1 += fmaxf(acc01[reg] + bc1, 0.f) + fmaxf(acc11[reg] + bc1, 0.f);
            }
            cs0 += __shfl_xor(cs0, 32);
            cs1 += __shfl_xor(cs1, 32);
            if (hi == 0) {
                float* pp = partial + ((size_t)blk*2 + rh)*256;
                pp[colA] = cs0;
                pp[colB] = cs1;
            }
        }
    }
}

// ---------------------------------------- partial-reduce + f-MLP fused ----
__global__ void fmlp_kernel(const float* __restrict__ partial,
                            const float* __restrict__ Wf1, const float* __restrict__ bf1,
                            const float* __restrict__ Wf2, const float* __restrict__ bf2,
                            const float* __restrict__ Wf3, const float* __restrict__ bf3,
                            float* __restrict__ out)
{
    int b = blockIdx.x, tid = threadIdx.x;
    __shared__ float v0[256], v1[256], lgt[28];
    {
        float s0 = 0.f, s1 = 0.f, s2 = 0.f, s3 = 0.f;
        const float* p = partial + ((size_t)b * 64) * 256 + tid;
        #pragma unroll
        for (int k = 0; k < 64; k += 4) {
            s0 += p[(size_t)(k+0) * 256];
            s1 += p[(size_t)(k+1) * 256];
            s2 += p[(size_t)(k+2) * 256];
            s3 += p[(size_t)(k+3) * 256];
        }
        v0[tid] = (s0 + s1) + (s2 + s3);
    }
    __syncthreads();
    {
        float s = bf1[tid];
        const float4* wr = reinterpret_cast<const float4*>(Wf1 + (size_t)tid * 256);
        for (int k4 = 0; k4 < 64; ++k4) {
            float4 wv = wr[k4];
            s += wv.x*v0[k4*4+0] + wv.y*v0[k4*4+1] + wv.z*v0[k4*4+2] + wv.w*v0[k4*4+3];
        }
        v1[tid] = fmaxf(s, 0.f);
    }
    __syncthreads();
    {
        float s = bf2[tid];
        const float4* wr = reinterpret_cast<const float4*>(Wf2 + (size_t)tid * 256);
        for (int k4 = 0; k4 < 64; ++k4) {
            float4 wv = wr[k4];
            s += wv.x*v1[k4*4+0] + wv.y*v1[k4*4+1] + wv.z*v1[k4*4+2] + wv.w*v1[k4*4+3];
        }
        v0[tid] = fmaxf(s, 0.f);
    }
    __syncthreads();
    if (tid < 28) {
        float s = bf3[tid];
        const float4* wr = reinterpret_cast<const float4*>(Wf3 + (size_t)tid * 256);
        for (int k4 = 0; k4 < 64; ++k4) {
            float4 wv = wr[k4];
            s += wv.x*v0[k4*4+0] + wv.y*v0[k4*4+1] + wv.z*v0[k4*4+2] + wv.w*v0[k4*4+3];
        }
        lgt[tid] = s;
    }
    __syncthreads();
    if (tid == 0) {
        float mx = -1e30f;
        for (int i = 0; i < 28; ++i) mx = fmaxf(mx, lgt[i]);
        float se = 0.f;
        for (int i = 0; i < 28; ++i) se += expf(lgt[i] - mx);
        float lse = mx + logf(se);
        for (int i = 0; i < 28; ++i) out[b*28 + i] = lgt[i] - lse;
    }
}

// ------------------------------------------------------------- launch -----
extern "C" void kernel_launch(void* const* d_in, const int* in_sizes, int n_in,
                              void* d_out, int out_size, void* d_ws, size_t ws_size,
                              hipStream_t stream)
{
    (void)in_sizes; (void)n_in; (void)out_size; (void)ws_size;
    const float* img = (const float*)d_in[0];
    const int*   qidx= (const int*)  d_in[1];
    const float* emb = (const float*)d_in[2];
    const float* Wih = (const float*)d_in[3];
    const float* Whh = (const float*)d_in[4];
    const float* bih = (const float*)d_in[5];
    const float* bhh = (const float*)d_in[6];
    const float* k1  = (const float*)d_in[7];  const float* cb1=(const float*)d_in[8];
    const float* g1  = (const float*)d_in[9];  const float* be1=(const float*)d_in[10];
    const float* k2  = (const float*)d_in[11]; const float* cb2=(const float*)d_in[12];
    const float* g2  = (const float*)d_in[13]; const float* be2=(const float*)d_in[14];
    const float* k3  = (const float*)d_in[15]; const float* cb3=(const float*)d_in[16];
    const float* g3  = (const float*)d_in[17]; const float* be3=(const float*)d_in[18];
    const float* k4  = (const float*)d_in[19]; const float* cb4=(const float*)d_in[20];
    const float* g4  = (const float*)d_in[21]; const float* be4=(const float*)d_in[22];
    const float* Wg1 = (const float*)d_in[23]; const float* bg1=(const float*)d_in[24];
    const float* Wg2 = (const float*)d_in[25]; const float* bg2=(const float*)d_in[26];
    const float* Wg3 = (const float*)d_in[27]; const float* bg3=(const float*)d_in[28];
    const float* Wg4 = (const float*)d_in[29]; const float* bg4=(const float*)d_in[30];
    const float* Wf1 = (const float*)d_in[31]; const float* bf1=(const float*)d_in[32];
    const float* Wf2 = (const float*)d_in[33]; const float* bf2=(const float*)d_in[34];
    const float* Wf3 = (const float*)d_in[35]; const float* bf3=(const float*)d_in[36];
    const float* h0  = (const float*)d_in[37]; const float* c0 =(const float*)d_in[38];
    float* out = (float*)d_out;

    // workspace carve-up (floats), all 16B aligned
    float* ws = (float*)d_ws;
    float* y1 = ws;   ws += 64*24*64*64;
    float* y2 = ws;   ws += 64*24*32*32;
    float* y3 = ws;   ws += 64*24*16*16;
    float* y4 = ws;   ws += 64*24*8*8;
    float* bnp = ws;  ws += 24*16*2;
    float* qst = ws;  ws += 64*128;
    float* Ai  = ws;  ws += 64*64*256;
    float* Aj  = ws;  ws += 64*64*256;
    float* Qb  = ws;  ws += 64*256;
    unsigned short* Wt2 = (unsigned short*)ws; ws += 65536/2;
    unsigned short* Wt3 = (unsigned short*)ws; ws += 65536/2;
    unsigned short* Wt4 = (unsigned short*)ws; ws += 65536/2;
    float* WihT = ws; ws += 32*512;
    float* WhhT = ws; ws += 128*512;
    float* partial = ws; ws += 2048*2*256;

    cvt_kernel<<<544, 512, 0, stream>>>(Wg2, Wg3, Wg4, Wih, Whh, Wt2, Wt3, Wt4, WihT, WhhT);
    lstm_kernel<<<64, 512, 0, stream>>>(qidx, emb, WihT, WhhT, bih, bhh, h0, c0, qst);

    conv1_kernel<<<dim3(64, 16), 256, 0, stream>>>(img, k1, cb1, y1);
    bn_partial_kernel<<<dim3(24,16), 256, 0, stream>>>(y1, bnp, 64*64, 4);
    conv2_kernel<<<dim3(64, 16), 128, 0, stream>>>(y1, k2, cb2, bnp, g1, be1, y2);
    bn_partial_kernel<<<dim3(24,8), 256, 0, stream>>>(y2, bnp, 32*32, 8);
    conv_kernel<<<dim3(64*24, 1), 256, 0, stream>>>(y2, k3, cb3, bnp, g2, be2, 8, 64*32*32,
                                                    y3, 24, 32, 32, 16, 16);
    bn_partial_kernel<<<dim3(24,4), 256, 0, stream>>>(y3, bnp, 16*16, 16);
    conv_kernel<<<dim3(64*24, 1), 256, 0, stream>>>(y3, k4, cb4, bnp, g3, be3, 4, 64*16*16,
                                                    y4, 24, 16, 16, 8, 8);
    bn_partial_kernel<<<dim3(24,1), 256, 0, stream>>>(y4, bnp, 8*8, 64);

    aiajq_kernel<<<64, 256, 0, stream>>>(y4, bnp, g4, be4, qst, Wg1, bg1, Ai, Aj, Qb);

    gmlp_kernel<<<2048, 512, 0, stream>>>(Ai, Aj, Qb, Wt2, bg2, Wt3, bg3, Wt4, bg4, partial);
    fmlp_kernel<<<64, 256, 0, stream>>>(partial, Wf1, bf1, Wf2, bf2, Wf3, bf3, out);
}